// Round 6
// baseline (517.935 us; speedup 1.0000x reference)
//
#include <hip/hip_runtime.h>

// Palettized 3x3 VALID conv as implicit GEMM:
//   C[M=16*254*254, 64] = A[M, K=576] * B[K=576, 64],  K = (kh*3+kw)*64 + c
// Round-6: occupancy via ACCUMULATOR SPLIT, same tile & traffic as R0/R5.
// Model from R0-R5: sustained BW tracks resident waves (R2: 24 waves -> 3.78
// TB/s even under 5x spill traffic; all acc[4][4] variants: 64 AGPR + ~72
// VGPR = ~140 regs/wave -> 3 waves/SIMD -> 2.8 TB/s ceiling). Fix: 512-thread
// blocks, 8 waves; wave = 1 oh x 64 ow x 32 O -> acc[4][2] = 32 AGPR,
// ~68 regs total -> 6 waves/SIMD (launch_bounds cap 85). Same 4-oh block
// tile => zero extra halo traffic; O-split (not ow-split) keeps B-fragment
// L2 traffic at R0 level. Staging = R5's vectorized dwordx4 path per wave.

typedef __bf16 bf16x8 __attribute__((ext_vector_type(8)));
typedef float f32x4 __attribute__((ext_vector_type(4)));

union Frag {
    uint4 q;
    bf16x8 v;
};

// ---- B dequant/swizzle: Bws[s]  s = (kc*4 + nt)*64 + lane, 16B per slot.
// lane holds B[k = kc*32 + (lane>>4)*8 + j][o = nt*16 + (lane&15)], j=0..7
// with k = (kh*3+kw)*64 + c  ->  kc: r = kc>>1 fixed, c = (kc&1)*32 + (lane>>4)*8 + j.
__global__ __launch_bounds__(256) void dequant_B(
        const float* __restrict__ lut, const int* __restrict__ widx,
        uint4* __restrict__ Bws) {
    int s = blockIdx.x * 256 + threadIdx.x;   // 0..4607
    int l = s & 63;
    int nt = (s >> 6) & 3;
    int kc = s >> 8;
    if (kc >= 18) return;
    int r = kc >> 1;
    int kh = r / 3, kw = r - kh * 3;
    int o = nt * 16 + (l & 15);
    int c0 = (kc & 1) * 32 + (l >> 4) * 8;
    Frag f;
#pragma unroll
    for (int j = 0; j < 8; ++j) {
        int c = c0 + j;
        int idx = widx[((o * 64 + c) * 3 + kh) * 3 + kw];
        f.v[j] = (__bf16)lut[idx];
    }
    Bws[s] = f.q;
}

// LDS layout: ldsA[cblk][pix] as 16B granules; pix = row*66 + col (row 0..5, col 0..65)
// granule = 8 bf16 = channels cblk*8 .. cblk*8+7 of pixel (row,col);
// u32 word k of a granule = packed (ch 2k, ch 2k+1).
#define LDS_PIX 396

__global__ __launch_bounds__(512, 6) void conv_mfma(
        const float* __restrict__ x, const float* __restrict__ bias,
        const uint4* __restrict__ Bws, float* __restrict__ out) {
    __shared__ uint4 ldsA[8 * LDS_PIX];   // 50688 B -> 3 blocks/CU (24 waves)
    unsigned* lds32 = (unsigned*)ldsA;

    int bx = blockIdx.x;
    int ow0 = (bx & 3) * 64;          // 0,64,128,192
    int oh0 = ((bx >> 2) & 63) * 4;   // 0..252
    int n = bx >> 8;                  // 0..15
    int t = threadIdx.x;

    const float* xn = x + (size_t)n * (64 * 256 * 256);

    int w = t >> 6;                   // wave 0..7
    int l = t & 63;
    int l15 = l & 15, l4 = l >> 4;

    // ---- stage x[n, 0:64, oh0:oh0+6, ow0:ow0+66] -> LDS (fp32 -> bf16)
    // wave w -> cblk w; lane = (colg=l&15, chp=l>>4). Per row: lane loads
    // float4 (cols colg*4..+3) of channels chp*2, chp*2+1; 3-row chunks
    // (6 dwordx4 in flight/wave x 24 waves/CU).
    {
        int colg = l15, chp = l4;
        const float* cbase = xn + (w * 8 + chp * 2) * 65536 + ow0 + colg * 4;
#pragma unroll
        for (int ch = 0; ch < 2; ++ch) {
            f32x4 f0[3], f1[3];
#pragma unroll
            for (int rr = 0; rr < 3; ++rr) {
                int y = oh0 + ch * 3 + rr; if (y > 255) y = 255;
                const float* p = cbase + y * 256;
                f0[rr] = *(const f32x4*)(p);
                f1[rr] = *(const f32x4*)(p + 65536);
            }
#pragma unroll
            for (int rr = 0; rr < 3; ++rr) {
                int gbase = w * LDS_PIX + (ch * 3 + rr) * 66 + colg * 4;
#pragma unroll
                for (int i = 0; i < 4; ++i) {
                    union { __bf16 h[2]; unsigned u; } bp;
                    bp.h[0] = (__bf16)f0[rr][i];
                    bp.h[1] = (__bf16)f1[rr][i];
                    lds32[(gbase + i) * 4 + chp] = bp.u;
                }
            }
        }
        // tail: cols 64,65 (6 rows x 2 cols x 8 cblks = 96 granules), scalar path
        if (t < 96) {
            int cblk = t & 7;
            int rc = t >> 3;            // 0..11
            int rr = rc >> 1;
            int col2 = 64 + (rc & 1);
            int y = oh0 + rr; if (y > 255) y = 255;
            int xc = ow0 + col2; if (xc > 255) xc = 255;
            const float* src = xn + cblk * 8 * 65536 + y * 256 + xc;
            Frag f;
#pragma unroll
            for (int j = 0; j < 8; ++j)
                f.v[j] = (__bf16)src[j * 65536];
            ldsA[cblk * LDS_PIX + rr * 66 + col2] = f.q;
        }
    }
    __syncthreads();

    // ---- main GEMM: wave w -> oh row (oh0 + (w>>1)) x 64 ow x O-half (w&1)
    int ohl = w >> 1;                 // 0..3
    int oseg = (w & 1) * 2;           // B nt-offset: 0 or 2

    f32x4 acc[4][2] = {};

    for (int kc = 0; kc < 18; ++kc) {
        int r = kc >> 1;
        int kh = r / 3, kw = r - kh * 3;       // block-uniform
        int cblk = (kc & 1) * 4 + l4;
        int pix = (ohl + kh) * 66 + l15 + kw;

        Frag b[2];
#pragma unroll
        for (int nt = 0; nt < 2; ++nt)
            b[nt].q = Bws[(kc * 4 + oseg + nt) * 64 + l];

        Frag a[4];
#pragma unroll
        for (int mt = 0; mt < 4; ++mt)
            a[mt].q = ldsA[cblk * LDS_PIX + pix + mt * 16];

#pragma unroll
        for (int mt = 0; mt < 4; ++mt)
#pragma unroll
            for (int nt = 0; nt < 2; ++nt)
                acc[mt][nt] = __builtin_amdgcn_mfma_f32_16x16x32_bf16(
                    a[mt].v, b[nt].v, acc[mt][nt], 0, 0, 0);
    }

    // ---- epilogue: C/D layout col(o)=lane&15, row(ow_l)=(lane>>4)*4+reg
    int oh = oh0 + ohl;
    if (oh < 254) {
#pragma unroll
        for (int nt = 0; nt < 2; ++nt) {
            int o = (oseg + nt) * 16 + l15;
            float bv = bias[o];
            float* obase = out + (((size_t)n * 64 + o) * 254 + oh) * 254 + ow0;
#pragma unroll
            for (int mt = 0; mt < 4; ++mt) {
#pragma unroll
                for (int rg = 0; rg < 4; ++rg) {
                    int owl = mt * 16 + l4 * 4 + rg;
                    if (ow0 + owl < 254)
                        obase[owl] = acc[mt][nt][rg] + bv;
                }
            }
        }
    }
}

extern "C" void kernel_launch(void* const* d_in, const int* in_sizes, int n_in,
                              void* d_out, int out_size, void* d_ws, size_t ws_size,
                              hipStream_t stream) {
    const float* x    = (const float*)d_in[0];
    const float* lut  = (const float*)d_in[1];
    const int*   widx = (const int*)d_in[2];
    const float* bias = (const float*)d_in[3];
    float* out = (float*)d_out;
    uint4* Bws = (uint4*)d_ws;   // needs 73728 B

    dequant_B<<<18, 256, 0, stream>>>(lut, widx, Bws);
    conv_mfma<<<4096, 512, 0, stream>>>(x, bias, (const uint4*)Bws, out);
}

// Round 7
// 511.932 us; speedup vs baseline: 1.0117x; 1.0117x over previous
//
#include <hip/hip_runtime.h>

// Palettized 3x3 VALID conv as implicit GEMM:
//   C[M=16*254*254, 64] = A[M, K=576] * B[K=576, 64],  K = (kh*3+kw)*64 + c
// Round-7: R5 base (203us) + SEGMENT-COALESCED EPILOGUE.
// Diagnosis: BW wall ~2.8 TB/s invariant across occupancy 29-64% (R0-R6).
// Old epilogue store instr = 16 output planes x scattered dwords = ~16-32
// cache-line segments per instruction (~27% of memory-pipe cycles). R2's
// 3.78 TB/s run had segment-cheap (contiguous per-wave) spill stores ->
// segment cost, not bytes, is the wall. Fix: transpose acc through a
// wave-private LDS slab so each store is 64 lanes x 4B contiguous (1 segment).

typedef __bf16 bf16x8 __attribute__((ext_vector_type(8)));
typedef float f32x4 __attribute__((ext_vector_type(4)));

union Frag {
    uint4 q;
    bf16x8 v;
};

// ---- B dequant/swizzle: Bws[s]  s = (kc*4 + nt)*64 + lane, 16B per slot.
// lane holds B[k = kc*32 + (lane>>4)*8 + j][o = nt*16 + (lane&15)], j=0..7
// with k = (kh*3+kw)*64 + c  ->  kc: r = kc>>1 fixed, c = (kc&1)*32 + (lane>>4)*8 + j.
__global__ __launch_bounds__(256) void dequant_B(
        const float* __restrict__ lut, const int* __restrict__ widx,
        uint4* __restrict__ Bws) {
    int s = blockIdx.x * 256 + threadIdx.x;   // 0..4607
    int l = s & 63;
    int nt = (s >> 6) & 3;
    int kc = s >> 8;
    if (kc >= 18) return;
    int r = kc >> 1;
    int kh = r / 3, kw = r - kh * 3;
    int o = nt * 16 + (l & 15);
    int c0 = (kc & 1) * 32 + (l >> 4) * 8;
    Frag f;
#pragma unroll
    for (int j = 0; j < 8; ++j) {
        int c = c0 + j;
        int idx = widx[((o * 64 + c) * 3 + kh) * 3 + kw];
        f.v[j] = (__bf16)lut[idx];
    }
    Bws[s] = f.q;
}

// LDS layout: ldsA[cblk][pix] as 16B granules; pix = row*66 + col (row 0..5, col 0..65)
// granule = 8 bf16 = channels cblk*8 .. cblk*8+7 of pixel (row,col);
// u32 word k of a granule = packed (ch 2k, ch 2k+1).
#define LDS_PIX 396

__global__ __launch_bounds__(256, 3) void conv_mfma(
        const float* __restrict__ x, const float* __restrict__ bias,
        const uint4* __restrict__ Bws, float* __restrict__ out) {
    __shared__ uint4 ldsA[8 * LDS_PIX];   // 50688 B
    unsigned* lds32 = (unsigned*)ldsA;

    int bx = blockIdx.x;
    int ow0 = (bx & 3) * 64;          // 0,64,128,192
    int oh0 = ((bx >> 2) & 63) * 4;   // 0..252
    int n = bx >> 8;                  // 0..15
    int t = threadIdx.x;

    const float* xn = x + (size_t)n * (64 * 256 * 256);

    int w = t >> 6;
    int l = t & 63;
    int l15 = l & 15, l4 = l >> 4;

    // ---- stage x[n, 0:64, oh0:oh0+6, ow0:ow0+66] -> LDS (fp32 -> bf16)
    // main cols 0..63: wave w covers cblk {w, w+4}; lane = (colg=l&15, chp=l>>4).
    // Per cblk-row: lane loads float4 (cols colg*4..+3) of channels chp*2, chp*2+1,
    // writes 4 packed u32 into LDS. 6 rows batched -> 12 dwordx4 in flight/wave.
    {
        int colg = l15;
        int chp  = l4;                 // 0..3
        const float* xw = xn + ow0 + colg * 4;
#pragma unroll
        for (int cc = 0; cc < 2; ++cc) {
            int cb = w + cc * 4;       // wave-uniform cblk
            const float* cbase = xw + (cb * 8 + chp * 2) * 65536;
            f32x4 f0[6], f1[6];
#pragma unroll
            for (int rr = 0; rr < 6; ++rr) {
                int y = oh0 + rr; if (y > 255) y = 255;
                const float* p = cbase + y * 256;
                f0[rr] = *(const f32x4*)(p);
                f1[rr] = *(const f32x4*)(p + 65536);
            }
#pragma unroll
            for (int rr = 0; rr < 6; ++rr) {
                int gbase = cb * LDS_PIX + rr * 66 + colg * 4;
#pragma unroll
                for (int i = 0; i < 4; ++i) {
                    union { __bf16 h[2]; unsigned u; } bp;
                    bp.h[0] = (__bf16)f0[rr][i];
                    bp.h[1] = (__bf16)f1[rr][i];
                    lds32[(gbase + i) * 4 + chp] = bp.u;
                }
            }
        }
        // tail: cols 64,65 (6 rows x 2 cols x 8 cblks = 96 granules), scalar path
        if (t < 96) {
            int cblk = t & 7;
            int rc = t >> 3;            // 0..11
            int rr = rc >> 1;
            int col2 = 64 + (rc & 1);
            int y = oh0 + rr; if (y > 255) y = 255;
            int xc = ow0 + col2; if (xc > 255) xc = 255;
            const float* src = xn + cblk * 8 * 65536 + y * 256 + xc;
            Frag f;
#pragma unroll
            for (int j = 0; j < 8; ++j)
                f.v[j] = (__bf16)src[j * 65536];
            ldsA[cblk * LDS_PIX + rr * 66 + col2] = f.q;
        }
    }
    __syncthreads();

    // ---- main GEMM: wave w handles oh row (oh0+w) x 64 ow x 64 O
    f32x4 acc[4][4] = {};

    for (int kc = 0; kc < 18; ++kc) {
        int r = kc >> 1;
        int kh = r / 3, kw = r - kh * 3;       // block-uniform
        int cblk = (kc & 1) * 4 + l4;
        int pix = (w + kh) * 66 + l15 + kw;

        Frag b[4];
#pragma unroll
        for (int nt = 0; nt < 4; ++nt)
            b[nt].q = Bws[(kc * 4 + nt) * 64 + l];

        Frag a[4];
#pragma unroll
        for (int mt = 0; mt < 4; ++mt)
            a[mt].q = ldsA[cblk * LDS_PIX + pix + mt * 16];

#pragma unroll
        for (int mt = 0; mt < 4; ++mt)
#pragma unroll
            for (int nt = 0; nt < 4; ++nt)
                acc[mt][nt] = __builtin_amdgcn_mfma_f32_16x16x32_bf16(
                    a[mt].v, b[nt].v, acc[mt][nt], 0, 0, 0);
    }

    // ---- epilogue: transpose acc through wave-private LDS slab so every
    // global store is 64 lanes x 4B contiguous (one 256B segment).
    // acc C/D layout: lane l holds out[o=nt*16+l15][oh0+w][ow0+mt*16+l4*4+rg].
    __syncthreads();                       // everyone done reading ldsA
    float* slab = (float*)ldsA + w * (16 * 65);   // 4160 B per wave, reused per nt

    int oh = oh0 + w;
    if (oh < 254) {
        float* orow = out + (((size_t)n * 64) * 254 + oh) * 254 + ow0;
        bool colok = (ow0 + l) < 254;
#pragma unroll
        for (int nt = 0; nt < 4; ++nt) {
            // scatter this nt's 16 values into slab[o16][ow64] (pitch 65)
#pragma unroll
            for (int mt = 0; mt < 4; ++mt)
#pragma unroll
                for (int rg = 0; rg < 4; ++rg)
                    slab[l15 * 65 + mt * 16 + l4 * 4 + rg] = acc[mt][nt][rg];
            // gather transposed: lane l = column ow0+l, row j = plane nt*16+j
#pragma unroll
            for (int j = 0; j < 16; ++j) {
                int o = nt * 16 + j;
                float v = slab[j * 65 + l] + bias[o];
                if (colok)
                    orow[(size_t)o * (254 * 254) + l] = v;
            }
        }
    }
}

extern "C" void kernel_launch(void* const* d_in, const int* in_sizes, int n_in,
                              void* d_out, int out_size, void* d_ws, size_t ws_size,
                              hipStream_t stream) {
    const float* x    = (const float*)d_in[0];
    const float* lut  = (const float*)d_in[1];
    const int*   widx = (const int*)d_in[2];
    const float* bias = (const float*)d_in[3];
    float* out = (float*)d_out;
    uint4* Bws = (uint4*)d_ws;   // needs 73728 B

    dequant_B<<<18, 256, 0, stream>>>(lut, widx, Bws);
    conv_mfma<<<4096, 256, 0, stream>>>(x, bias, (const uint4*)Bws, out);
}